// Round 1
// baseline (575.293 us; speedup 1.0000x reference)
//
#include <hip/hip_runtime.h>
#include <stdint.h>

typedef __bf16 bf16_t;
typedef __attribute__((ext_vector_type(8))) __bf16 bf16x8;
typedef __attribute__((ext_vector_type(4))) float f32x4;
typedef __attribute__((ext_vector_type(8))) unsigned short ushort8;
typedef __attribute__((ext_vector_type(4))) int int4v;
typedef __attribute__((ext_vector_type(4))) float float4v;

typedef const void __attribute__((address_space(1)))* gptr_t;
typedef void __attribute__((address_space(3)))* lptr_t;

__constant__ float NF4_CB[16] = {
    -1.0f, -0.6961928009986877f, -0.5250730514526367f, -0.39491748809814453f,
    -0.28444138169288635f, -0.18477343022823334f, -0.09105003625154495f, 0.0f,
    0.07958029955625534f, 0.16093020141124725f, 0.24611230194568634f,
    0.33791524171829224f, 0.44070982933044434f, 0.5626170039176941f,
    0.6848514676094055f, 1.0f};

__device__ __forceinline__ unsigned short f32_to_bf16_rne(float f) {
    unsigned int u = __float_as_uint(f);
    u += 0x7FFFu + ((u >> 16) & 1u);
    return (unsigned short)(u >> 16);
}

// Dequantize W: each thread handles 8 codes (all within one 64-elem absmax block).
__global__ void dequant_w_kernel(const int* __restrict__ codes,
                                 const float* __restrict__ absmax,
                                 unsigned short* __restrict__ out, long n8) {
    long t = (long)blockIdx.x * blockDim.x + threadIdx.x;
    if (t >= n8) return;
    long base = t * 8;
    float am = absmax[t >> 3];   // (t*8)/64
    int4v c0 = *(const int4v*)(codes + base);
    int4v c1 = *(const int4v*)(codes + base + 4);
    ushort8 v;
    v[0] = f32_to_bf16_rne(NF4_CB[c0[0]] * am);
    v[1] = f32_to_bf16_rne(NF4_CB[c0[1]] * am);
    v[2] = f32_to_bf16_rne(NF4_CB[c0[2]] * am);
    v[3] = f32_to_bf16_rne(NF4_CB[c0[3]] * am);
    v[4] = f32_to_bf16_rne(NF4_CB[c1[0]] * am);
    v[5] = f32_to_bf16_rne(NF4_CB[c1[1]] * am);
    v[6] = f32_to_bf16_rne(NF4_CB[c1[2]] * am);
    v[7] = f32_to_bf16_rne(NF4_CB[c1[3]] * am);
    *(ushort8*)(out + base) = v;
}

// Convert x fp32 -> bf16, 8 elems/thread.
__global__ void cvt_x_kernel(const float* __restrict__ x,
                             unsigned short* __restrict__ out, long n8) {
    long t = (long)blockIdx.x * blockDim.x + threadIdx.x;
    if (t >= n8) return;
    long base = t * 8;
    float4v f0 = *(const float4v*)(x + base);
    float4v f1 = *(const float4v*)(x + base + 4);
    ushort8 v;
    v[0] = f32_to_bf16_rne(f0[0]);
    v[1] = f32_to_bf16_rne(f0[1]);
    v[2] = f32_to_bf16_rne(f0[2]);
    v[3] = f32_to_bf16_rne(f0[3]);
    v[4] = f32_to_bf16_rne(f1[0]);
    v[5] = f32_to_bf16_rne(f1[1]);
    v[6] = f32_to_bf16_rne(f1[2]);
    v[7] = f32_to_bf16_rne(f1[3]);
    *(ushort8*)(out + base) = v;
}

__global__ void bias_kernel(const int* __restrict__ bc,
                            const float* __restrict__ bam,
                            float* __restrict__ bias, int n) {
    int o = blockIdx.x * blockDim.x + threadIdx.x;
    if (o >= n) return;
    bias[o] = NF4_CB[bc[o]] * bam[o >> 6];
}

// C[m][n] = sum_k A[m][k] * B[n][k] + bias[n]
// A: [M,K] bf16 row-major; B: [N,K] bf16 row-major (W as dequantized, already "B^T" form).
// 128x128 tile per 256-thread block; BK=32; 4 waves in 2x2, each computes 64x64
// via 4x4 grid of 16x16x32 bf16 MFMA.
__global__ void gemm_bias_kernel(const bf16_t* __restrict__ A,
                                 const bf16_t* __restrict__ B,
                                 const float* __restrict__ bias,
                                 float* __restrict__ C,
                                 int M, int N, int K) {
    // sA = [0,4096): 128 rows x 32 elems; sB = [4096,8192): same.
    __shared__ __align__(16) bf16_t sAB[8192];

    const int t = threadIdx.x;
    const int lane = t & 63;
    const int wave = t >> 6;
    const int tileM = blockIdx.y * 128;
    const int tileN = blockIdx.x * 128;

    // Staging: 16 chunks of 1KB (64 lanes x 16B). Chunks 0..7 = A rows, 8..15 = B rows.
    // Wave w stages chunks w*4 .. w*4+3. Lane i of chunk c writes LDS byte c*1024+i*16,
    // i.e. row c*16 + (i>>2), k-offset (i&3)*8 — glds dest is wave-uniform base + lane*16.
    const bf16_t* src[4];
    bf16_t* ldst[4];
#pragma unroll
    for (int j = 0; j < 4; ++j) {
        int chunk = wave * 4 + j;
        int r = (chunk & 7) * 16 + (lane >> 2);
        int kk = (lane & 3) * 8;
        const bf16_t* base = (chunk < 8) ? (A + (size_t)(tileM + r) * K)
                                         : (B + (size_t)(tileN + r) * K);
        src[j] = base + kk;
        ldst[j] = &sAB[chunk * 512 + lane * 8];
    }

    const int wm = wave >> 1;
    const int wn = wave & 1;
    // A-operand layout: lane holds A[m = lane&15][k = (lane>>4)*8 + j], j=0..7 contiguous.
    const int aoff = (wm * 64 + (lane & 15)) * 32 + (lane >> 4) * 8;
    const int boff = 4096 + (wn * 64 + (lane & 15)) * 32 + (lane >> 4) * 8;

    f32x4 acc[4][4] = {};

    for (int kt = 0; kt < K; kt += 32) {
#pragma unroll
        for (int j = 0; j < 4; ++j) {
            __builtin_amdgcn_global_load_lds((gptr_t)(src[j]), (lptr_t)(ldst[j]),
                                             16, 0, 0);
            src[j] += 32;
        }
        __syncthreads();   // drains vmcnt before barrier

        bf16x8 a[4], b[4];
#pragma unroll
        for (int i = 0; i < 4; ++i) a[i] = *(const bf16x8*)&sAB[aoff + i * 512];
#pragma unroll
        for (int i = 0; i < 4; ++i) b[i] = *(const bf16x8*)&sAB[boff + i * 512];
#pragma unroll
        for (int mi = 0; mi < 4; ++mi)
#pragma unroll
            for (int ni = 0; ni < 4; ++ni)
                acc[mi][ni] = __builtin_amdgcn_mfma_f32_16x16x32_bf16(
                    a[mi], b[ni], acc[mi][ni], 0, 0, 0);
        __syncthreads();   // LDS reused next iteration
    }

    // C/D layout: col = lane&15, row = (lane>>4)*4 + reg.
    const int col0 = tileN + wn * 64 + (lane & 15);
    const int row0 = tileM + wm * 64 + (lane >> 4) * 4;
    float bv[4];
#pragma unroll
    for (int ni = 0; ni < 4; ++ni) bv[ni] = bias[col0 + ni * 16];
#pragma unroll
    for (int mi = 0; mi < 4; ++mi)
#pragma unroll
        for (int ni = 0; ni < 4; ++ni)
#pragma unroll
            for (int r = 0; r < 4; ++r)
                C[(size_t)(row0 + mi * 16 + r) * N + (col0 + ni * 16)] =
                    acc[mi][ni][r] + bv[ni];
}

extern "C" void kernel_launch(void* const* d_in, const int* in_sizes, int n_in,
                              void* d_out, int out_size, void* d_ws, size_t ws_size,
                              hipStream_t stream) {
    const float* x        = (const float*)d_in[0];
    const int*   w_codes  = (const int*)d_in[1];
    const float* w_absmax = (const float*)d_in[2];
    const int*   b_codes  = (const int*)d_in[3];
    const float* b_absmax = (const float*)d_in[4];
    float* out = (float*)d_out;

    const int  D_OUT = in_sizes[3];                 // 4096
    const long WK    = (long)in_sizes[1];           // D_OUT*D_IN
    const int  D_IN  = (int)(WK / D_OUT);           // 4096
    const long xN    = (long)in_sizes[0];           // M*D_IN
    const int  M     = (int)(xN / D_IN);            // 8192
    const int  N = D_OUT, K = D_IN;

    // Workspace: W_bf16 [N*K] | A_bf16 [M*K] | bias_f32 [N]
    unsigned short* wsW = (unsigned short*)d_ws;
    unsigned short* wsA = wsW + (size_t)N * K;
    float* wsBias = (float*)(wsA + (size_t)M * K);

    long w8 = WK / 8;
    dequant_w_kernel<<<dim3((unsigned)((w8 + 255) / 256)), dim3(256), 0, stream>>>(
        w_codes, w_absmax, wsW, w8);

    long x8 = xN / 8;
    cvt_x_kernel<<<dim3((unsigned)((x8 + 255) / 256)), dim3(256), 0, stream>>>(
        x, wsA, x8);

    bias_kernel<<<dim3((N + 255) / 256), dim3(256), 0, stream>>>(
        b_codes, b_absmax, wsBias, N);

    gemm_bias_kernel<<<dim3(N / 128, M / 128), dim3(256), 0, stream>>>(
        (const bf16_t*)wsA, (const bf16_t*)wsW, wsBias, out, M, N, K);
}

// Round 2
// 522.531 us; speedup vs baseline: 1.1010x; 1.1010x over previous
//
#include <hip/hip_runtime.h>
#include <stdint.h>

typedef __bf16 bf16_t;
typedef __attribute__((ext_vector_type(8))) __bf16 bf16x8;
typedef __attribute__((ext_vector_type(4))) float f32x4;
typedef __attribute__((ext_vector_type(8))) unsigned short ushort8;
typedef __attribute__((ext_vector_type(4))) int int4v;
typedef __attribute__((ext_vector_type(4))) float float4v;

typedef const void __attribute__((address_space(1)))* gptr_t;
typedef void __attribute__((address_space(3)))* lptr_t;

__constant__ float NF4_CB[16] = {
    -1.0f, -0.6961928009986877f, -0.5250730514526367f, -0.39491748809814453f,
    -0.28444138169288635f, -0.18477343022823334f, -0.09105003625154495f, 0.0f,
    0.07958029955625534f, 0.16093020141124725f, 0.24611230194568634f,
    0.33791524171829224f, 0.44070982933044434f, 0.5626170039176941f,
    0.6848514676094055f, 1.0f};

__device__ __forceinline__ unsigned short f32_to_bf16_rne(float f) {
    unsigned int u = __float_as_uint(f);
    u += 0x7FFFu + ((u >> 16) & 1u);
    return (unsigned short)(u >> 16);
}

// Fused preprocessing: one launch covering W-dequant, X-convert, bias-dequant.
// Block ranges: [0, wb) -> W, [wb, wb+xb) -> X, [wb+xb, ...) -> bias.
__global__ void prep_kernel(const int* __restrict__ w_codes,
                            const float* __restrict__ w_absmax,
                            const float* __restrict__ x,
                            const int* __restrict__ b_codes,
                            const float* __restrict__ b_absmax,
                            unsigned short* __restrict__ outW,
                            unsigned short* __restrict__ outA,
                            float* __restrict__ outBias,
                            long w8, long x8, int nbias, long wb, long xb) {
    long blk = blockIdx.x;
    if (blk < wb) {
        long t = blk * blockDim.x + threadIdx.x;
        if (t >= w8) return;
        long base = t * 8;
        float am = w_absmax[t >> 3];
        int4v c0 = *(const int4v*)(w_codes + base);
        int4v c1 = *(const int4v*)(w_codes + base + 4);
        ushort8 v;
        v[0] = f32_to_bf16_rne(NF4_CB[c0[0]] * am);
        v[1] = f32_to_bf16_rne(NF4_CB[c0[1]] * am);
        v[2] = f32_to_bf16_rne(NF4_CB[c0[2]] * am);
        v[3] = f32_to_bf16_rne(NF4_CB[c0[3]] * am);
        v[4] = f32_to_bf16_rne(NF4_CB[c1[0]] * am);
        v[5] = f32_to_bf16_rne(NF4_CB[c1[1]] * am);
        v[6] = f32_to_bf16_rne(NF4_CB[c1[2]] * am);
        v[7] = f32_to_bf16_rne(NF4_CB[c1[3]] * am);
        *(ushort8*)(outW + base) = v;
    } else if (blk < wb + xb) {
        long t = (blk - wb) * blockDim.x + threadIdx.x;
        if (t >= x8) return;
        long base = t * 8;
        float4v f0 = *(const float4v*)(x + base);
        float4v f1 = *(const float4v*)(x + base + 4);
        ushort8 v;
        v[0] = f32_to_bf16_rne(f0[0]);
        v[1] = f32_to_bf16_rne(f0[1]);
        v[2] = f32_to_bf16_rne(f0[2]);
        v[3] = f32_to_bf16_rne(f0[3]);
        v[4] = f32_to_bf16_rne(f1[0]);
        v[5] = f32_to_bf16_rne(f1[1]);
        v[6] = f32_to_bf16_rne(f1[2]);
        v[7] = f32_to_bf16_rne(f1[3]);
        *(ushort8*)(outA + base) = v;
    } else {
        int o = (int)(blk - wb - xb) * blockDim.x + threadIdx.x;
        if (o >= nbias) return;
        outBias[o] = NF4_CB[b_codes[o]] * b_absmax[o >> 6];
    }
}

// C[m][n] = sum_k A[m][k]*B[n][k] + bias[n].
// 128x128 tile, BK=64, XOR-swizzled LDS (conflict-free ds_read_b128),
// global_load_lds width=16 staging, 4 waves in 2x2 each 64x64 via 16x16x32 MFMA.
//
// LDS layout: row r (0..127), k-chunk j (0..7, 16B each) stored at
//   region + r*128B + (j ^ (r&7))*16B.
// Staging chunk ci (1KB = 8 rows): lane i writes LDS ci*1024 + i*16, which is
// row ci*8+(i>>3), slot jj=i&7 -> must hold global k-chunk j=(i&7)^(i>>3).
// The permutation stays inside each row's 128B, so glds global reads remain
// 8 contiguous 128B segments per instruction.
__global__ void gemm_bias_kernel(const bf16_t* __restrict__ A,
                                 const bf16_t* __restrict__ B,
                                 const float* __restrict__ bias,
                                 float* __restrict__ C,
                                 int M, int N, int K) {
    __shared__ __align__(16) bf16_t sAB[16384];   // 32 KB: A [0,8192), B [8192,16384) elems

    const int t = threadIdx.x;
    const int lane = t & 63;
    const int wave = t >> 6;
    const int tileM = blockIdx.y * 128;
    const int tileN = blockIdx.x * 128;

    // Staging: 32 chunks of 1KB; wave w owns chunks w*8 .. w*8+7.
    // Waves 0,1 -> A (chunks 0..15), waves 2,3 -> B (chunks 16..31).
    const int rloc = lane >> 3;                  // row within 8-row chunk
    const int jsw  = (lane & 7) ^ rloc;          // global k-chunk this lane loads
    const int chunk0 = wave * 8;
    const int isB = chunk0 >> 4;
    const int ci0 = chunk0 & 15;
    const int r0 = ci0 * 8 + rloc;
    const bf16_t* srcp = (isB ? (B + (size_t)(tileN + r0) * K)
                              : (A + (size_t)(tileM + r0) * K)) + jsw * 8;
    bf16_t* dstp = &sAB[isB * 8192 + ci0 * 512 + lane * 8];
    const size_t srcChunkStride = (size_t)8 * K;  // 8 rows per chunk

    const int wm = wave >> 1;
    const int wn = wave & 1;
    const int la = lane & 15;
    const int jA = lane >> 4;                    // base k-chunk (within 32-k half)
    const int jj0 = (jA ^ (lane & 7)) * 8;       // swizzled element offset; kh=1 -> ^32
    const int aoff = (wm * 64 + la) * 64 + jj0;          // row stride = 64 elems (128B)
    const int boff = 8192 + (wn * 64 + la) * 64 + jj0;

    f32x4 acc[4][4] = {};

    for (int kt = 0; kt < K; kt += 64) {
#pragma unroll
        for (int j8 = 0; j8 < 8; ++j8)
            __builtin_amdgcn_global_load_lds((gptr_t)(srcp + j8 * srcChunkStride),
                                             (lptr_t)(dstp + j8 * 512), 16, 0, 0);
        srcp += 64;
        __syncthreads();

#pragma unroll
        for (int kh = 0; kh < 2; ++kh) {
            const int kx = kh * 32;              // flips bit 5 of the jj field
            bf16x8 a[4], b[4];
#pragma unroll
            for (int i = 0; i < 4; ++i) a[i] = *(const bf16x8*)&sAB[(aoff + i * 1024) ^ kx];
#pragma unroll
            for (int i = 0; i < 4; ++i) b[i] = *(const bf16x8*)&sAB[(boff + i * 1024) ^ kx];
#pragma unroll
            for (int mi = 0; mi < 4; ++mi)
#pragma unroll
                for (int ni = 0; ni < 4; ++ni)
                    acc[mi][ni] = __builtin_amdgcn_mfma_f32_16x16x32_bf16(
                        a[mi], b[ni], acc[mi][ni], 0, 0, 0);
        }
        __syncthreads();
    }

    // C/D layout: col = lane&15, row = (lane>>4)*4 + reg.
    const int col0 = tileN + wn * 64 + la;
    const int row0 = tileM + wm * 64 + jA * 4;
    float bv[4];
#pragma unroll
    for (int ni = 0; ni < 4; ++ni) bv[ni] = bias[col0 + ni * 16];
#pragma unroll
    for (int mi = 0; mi < 4; ++mi)
#pragma unroll
        for (int ni = 0; ni < 4; ++ni)
#pragma unroll
            for (int r = 0; r < 4; ++r)
                C[(size_t)(row0 + mi * 16 + r) * N + (col0 + ni * 16)] =
                    acc[mi][ni][r] + bv[ni];
}

extern "C" void kernel_launch(void* const* d_in, const int* in_sizes, int n_in,
                              void* d_out, int out_size, void* d_ws, size_t ws_size,
                              hipStream_t stream) {
    const float* x        = (const float*)d_in[0];
    const int*   w_codes  = (const int*)d_in[1];
    const float* w_absmax = (const float*)d_in[2];
    const int*   b_codes  = (const int*)d_in[3];
    const float* b_absmax = (const float*)d_in[4];
    float* out = (float*)d_out;

    const int  D_OUT = in_sizes[3];                 // 4096
    const long WK    = (long)in_sizes[1];           // D_OUT*D_IN
    const int  D_IN  = (int)(WK / D_OUT);           // 4096
    const long xN    = (long)in_sizes[0];           // M*D_IN
    const int  M     = (int)(xN / D_IN);            // 8192
    const int  N = D_OUT, K = D_IN;

    // Workspace: W_bf16 [N*K] | A_bf16 [M*K] | bias_f32 [N]
    unsigned short* wsW = (unsigned short*)d_ws;
    unsigned short* wsA = wsW + (size_t)N * K;
    float* wsBias = (float*)(wsA + (size_t)M * K);

    long w8 = WK / 8;
    long x8 = xN / 8;
    long wb = (w8 + 255) / 256;
    long xb = (x8 + 255) / 256;
    long bb = (D_OUT + 255) / 256;
    prep_kernel<<<dim3((unsigned)(wb + xb + bb)), dim3(256), 0, stream>>>(
        w_codes, w_absmax, x, b_codes, b_absmax, wsW, wsA, wsBias,
        w8, x8, D_OUT, wb, xb);

    gemm_bias_kernel<<<dim3(N / 128, M / 128), dim3(256), 0, stream>>>(
        (const bf16_t*)wsA, (const bf16_t*)wsW, wsBias, out, M, N, K);
}